// Round 2
// baseline (6347.872 us; speedup 1.0000x reference)
//
#include <hip/hip_runtime.h>
#include <hip/hip_fp16.h>
#include <cstdint>

// Problem constants
#define T_  256
#define B_  64
#define I_  1024
#define H_  1024
#define E_  4
#define C_  128
#define G4  4096   // 4*H

typedef _Float16 f16;
typedef _Float16 f16x8 __attribute__((ext_vector_type(8)));
typedef float    f32x4 __attribute__((ext_vector_type(4)));

__device__ __forceinline__ float sigmoidf_(float x) { return 1.f / (1.f + __expf(-x)); }

// ---------------- conversion f32 -> f16 (vectorized, grid-stride) -------------
__global__ void k_f32_to_f16(const float* __restrict__ src, f16* __restrict__ dst, int n8) {
    int i = blockIdx.x * blockDim.x + threadIdx.x;
    int stride = gridDim.x * blockDim.x;
    for (; i < n8; i += stride) {
        const float4* s = reinterpret_cast<const float4*>(src) + (size_t)i * 2;
        float4 a = s[0], b = s[1];
        f16x8 v = { (f16)a.x, (f16)a.y, (f16)a.z, (f16)a.w,
                    (f16)b.x, (f16)b.y, (f16)b.z, (f16)b.w };
        *reinterpret_cast<f16x8*>(dst + (size_t)i * 8) = v;
    }
}

// ---------------- mixed biases: gbias = coef@(bi+bh), bom = coef@bo ----------
__global__ void k_mix_biases(const float* __restrict__ coef, const float* __restrict__ bi,
                             const float* __restrict__ bh, const float* __restrict__ bo,
                             float* __restrict__ gbias, float* __restrict__ bom) {
    int idx = blockIdx.x * blockDim.x + threadIdx.x;
    int stride = gridDim.x * blockDim.x;
    for (int i = idx; i < B_ * G4; i += stride) {
        int b = i >> 12, o = i & (G4 - 1);
        float s = 0.f;
#pragma unroll
        for (int e = 0; e < 4; ++e) s += coef[b * 4 + e] * (bi[e * G4 + o] + bh[e * G4 + o]);
        gbias[i] = s;
    }
    for (int i = idx; i < B_ * C_; i += stride) {
        int b = i >> 7, c = i & (C_ - 1);
        float s = 0.f;
#pragma unroll
        for (int e = 0; e < 4; ++e) s += coef[b * 4 + e] * bo[e * C_ + c];
        bom[i] = s;
    }
}

// ---------------- state init -------------------------------------------------
__global__ void k_init_state(const float* __restrict__ h0, const float* __restrict__ c0,
                             float* __restrict__ hstate, float* __restrict__ cstate,
                             f16* __restrict__ h0h) {
    int i = blockIdx.x * blockDim.x + threadIdx.x;
    if (i < B_ * H_) {
        float h = h0[i];
        hstate[i] = h; cstate[i] = c0[i]; h0h[i] = (f16)h;
    }
}

// ---------------- xi GEMM: per-sample mixed input projection -----------------
// Per block: b fixed, all T=256 rows, 128 output cols; weights mixed during
// staging, so FLOPs = 137G not 549G. Templated on whether x / Wi have been
// pre-converted to f16 (workspace-size dependent).
template<bool XF16, bool WF16>
__global__ __launch_bounds__(256, 1) void k_xi_gemm(
        const f16* __restrict__ xh, const float* __restrict__ xf,
        const f16* __restrict__ Wih, const float* __restrict__ Wif,
        const float* __restrict__ coef, const float* __restrict__ gbias,
        f16* __restrict__ xi) {
    __shared__ f16 As[256 * 72];
    __shared__ f16 Bs[128 * 72];
    const int nt = blockIdx.x;      // 0..31  (128-col tile of 4096)
    const int b  = blockIdx.y;      // 0..63
    const int tid = threadIdx.x;
    const int lane = tid & 63, wave = tid >> 6;
    const int wr = wave >> 1, wc = wave & 1;

    float cf[4];
#pragma unroll
    for (int e = 0; e < 4; ++e) cf[e] = coef[b * 4 + e];

    f32x4 acc[8][4];
#pragma unroll
    for (int mi = 0; mi < 8; ++mi)
#pragma unroll
        for (int ni = 0; ni < 4; ++ni) acc[mi][ni] = 0.f;

    for (int kk = 0; kk < I_; kk += 64) {
        __syncthreads();
        // stage A: x[t, b, kk..kk+64)  (256 rows x 64)
#pragma unroll
        for (int it = 0; it < 8; ++it) {
            int chunk = it * 256 + tid;
            int row = chunk >> 3, c8 = chunk & 7;
            if constexpr (XF16) {
                *reinterpret_cast<f16x8*>(&As[row * 72 + c8 * 8]) =
                    *reinterpret_cast<const f16x8*>(&xh[((size_t)row * B_ + b) * I_ + kk + c8 * 8]);
            } else {
                const float4* p = reinterpret_cast<const float4*>(&xf[((size_t)row * B_ + b) * I_ + kk + c8 * 8]);
                float4 a = p[0], bq = p[1];
                f16x8 v = { (f16)a.x, (f16)a.y, (f16)a.z, (f16)a.w,
                            (f16)bq.x, (f16)bq.y, (f16)bq.z, (f16)bq.w };
                *reinterpret_cast<f16x8*>(&As[row * 72 + c8 * 8]) = v;
            }
        }
        // stage B mixed: sum_e coef[b,e]*Wi[e, col, kk..]  (128 rows x 64)
#pragma unroll
        for (int it = 0; it < 4; ++it) {
            int chunk = it * 256 + tid;
            int n = chunk >> 3, c8 = chunk & 7;
            if constexpr (WF16) {
                size_t base = ((size_t)(nt * 128 + n)) * I_ + kk + c8 * 8;
                f16 c0 = (f16)cf[0], c1 = (f16)cf[1], c2 = (f16)cf[2], c3 = (f16)cf[3];
                f16x8 w0 = *reinterpret_cast<const f16x8*>(&Wih[base]);
                f16x8 w1 = *reinterpret_cast<const f16x8*>(&Wih[base + (size_t)1 * G4 * I_]);
                f16x8 w2 = *reinterpret_cast<const f16x8*>(&Wih[base + (size_t)2 * G4 * I_]);
                f16x8 w3 = *reinterpret_cast<const f16x8*>(&Wih[base + (size_t)3 * G4 * I_]);
                f16x8 m = w0 * c0 + w1 * c1 + w2 * c2 + w3 * c3;
                *reinterpret_cast<f16x8*>(&Bs[n * 72 + c8 * 8]) = m;
            } else {
                size_t base = ((size_t)(nt * 128 + n)) * I_ + kk + c8 * 8;
                float m[8];
#pragma unroll
                for (int j = 0; j < 8; ++j) m[j] = 0.f;
#pragma unroll
                for (int e = 0; e < 4; ++e) {
                    const float4* p = reinterpret_cast<const float4*>(&Wif[base + (size_t)e * G4 * I_]);
                    float4 a = p[0], bq = p[1];
                    m[0] += cf[e] * a.x;  m[1] += cf[e] * a.y;
                    m[2] += cf[e] * a.z;  m[3] += cf[e] * a.w;
                    m[4] += cf[e] * bq.x; m[5] += cf[e] * bq.y;
                    m[6] += cf[e] * bq.z; m[7] += cf[e] * bq.w;
                }
                f16x8 v = { (f16)m[0], (f16)m[1], (f16)m[2], (f16)m[3],
                            (f16)m[4], (f16)m[5], (f16)m[6], (f16)m[7] };
                *reinterpret_cast<f16x8*>(&Bs[n * 72 + c8 * 8]) = v;
            }
        }
        __syncthreads();
#pragma unroll
        for (int ks = 0; ks < 2; ++ks) {
            int ko = ks * 32 + (lane >> 4) * 8;
            f16x8 a[8], bb[4];
#pragma unroll
            for (int mi = 0; mi < 8; ++mi)
                a[mi] = *reinterpret_cast<const f16x8*>(&As[(wr * 128 + mi * 16 + (lane & 15)) * 72 + ko]);
#pragma unroll
            for (int ni = 0; ni < 4; ++ni)
                bb[ni] = *reinterpret_cast<const f16x8*>(&Bs[(wc * 64 + ni * 16 + (lane & 15)) * 72 + ko]);
#pragma unroll
            for (int mi = 0; mi < 8; ++mi)
#pragma unroll
                for (int ni = 0; ni < 4; ++ni)
                    acc[mi][ni] = __builtin_amdgcn_mfma_f32_16x16x32_f16(a[mi], bb[ni], acc[mi][ni], 0, 0, 0);
        }
    }
    // epilogue: add mixed bias (coef@(bi+bh) folded in), store f16
#pragma unroll
    for (int mi = 0; mi < 8; ++mi)
#pragma unroll
        for (int ni = 0; ni < 4; ++ni)
#pragma unroll
            for (int j = 0; j < 4; ++j) {
                int t = wr * 128 + mi * 16 + (lane >> 4) * 4 + j;
                int o = nt * 128 + wc * 64 + ni * 16 + (lane & 15);
                float v = acc[mi][ni][j] + gbias[b * G4 + o];
                xi[((size_t)t * B_ + b) * G4 + o] = (f16)v;
            }
}

// ---------------- recurrence step -------------------------------------------
// Block jb owns 16 h-columns: computes h_prev @ Wh^T for 4 gates x 4 experts
// (256 GEMM cols, K=1024), mixes with coef, adds xi, does the cell update.
// h[t] is stored INTO xi[t]'s gate-0 region (overlay; saves a 33.5MB buffer):
//  - block jb reads gate-0 cols jb*16..+16 before the barrier, writes the same
//    cols after it; other blocks touch disjoint columns -> race-free.
__global__ __launch_bounds__(256, 1) void k_rec_step(
        int t, const f16* __restrict__ Whh, const f16* __restrict__ h0h,
        f16* xi, const float* __restrict__ coef,
        float* __restrict__ hstate, float* __restrict__ cstate) {
    __shared__ f16 As[64 * 72];
    __shared__ f16 Bs[256 * 72];
    __shared__ float gl[4][64][16];
    __shared__ float cfs[64][4];
    const int jb = blockIdx.x;               // 0..63 (16 h-cols each)
    const int tid = threadIdx.x, lane = tid & 63, g = tid >> 6;  // wave = gate
    cfs[tid >> 2][tid & 3] = coef[tid];      // 256 coef values, one per thread

    const f16* hprev;
    size_t hstr;
    if (t == 0) { hprev = h0h;                          hstr = H_; }
    else        { hprev = xi + (size_t)(t - 1) * B_ * G4; hstr = G4; }  // h in gate-0 of xi[t-1]

    f32x4 acc[4][4];
#pragma unroll
    for (int e = 0; e < 4; ++e)
#pragma unroll
        for (int mi = 0; mi < 4; ++mi) acc[e][mi] = 0.f;

    for (int kk = 0; kk < H_; kk += 64) {
        __syncthreads();
#pragma unroll
        for (int it = 0; it < 2; ++it) {   // A: h_prev 64x64
            int chunk = it * 256 + tid;
            int row = chunk >> 3, c8 = chunk & 7;
            *reinterpret_cast<f16x8*>(&As[row * 72 + c8 * 8]) =
                *reinterpret_cast<const f16x8*>(&hprev[(size_t)row * hstr + kk + c8 * 8]);
        }
#pragma unroll
        for (int it = 0; it < 8; ++it) {   // B: Wh rows for (e,g,jb) 256x64
            int chunk = it * 256 + tid;
            int r = chunk >> 3, c8 = chunk & 7;
            int e = r >> 6, gg = (r >> 4) & 3, n = r & 15;
            size_t grow = (size_t)e * G4 + gg * H_ + jb * 16 + n;
            *reinterpret_cast<f16x8*>(&Bs[r * 72 + c8 * 8]) =
                *reinterpret_cast<const f16x8*>(&Whh[grow * H_ + kk + c8 * 8]);
        }
        __syncthreads();
#pragma unroll
        for (int ks = 0; ks < 2; ++ks) {
            int ko = ks * 32 + (lane >> 4) * 8;
            f16x8 a[4];
#pragma unroll
            for (int mi = 0; mi < 4; ++mi)
                a[mi] = *reinterpret_cast<const f16x8*>(&As[(mi * 16 + (lane & 15)) * 72 + ko]);
#pragma unroll
            for (int e = 0; e < 4; ++e) {
                f16x8 bf = *reinterpret_cast<const f16x8*>(&Bs[((e * 4 + g) * 16 + (lane & 15)) * 72 + ko]);
#pragma unroll
                for (int mi = 0; mi < 4; ++mi)
                    acc[e][mi] = __builtin_amdgcn_mfma_f32_16x16x32_f16(a[mi], bf, acc[e][mi], 0, 0, 0);
            }
        }
    }
    // mix experts + add xi, park gate tile in LDS
#pragma unroll
    for (int mi = 0; mi < 4; ++mi)
#pragma unroll
        for (int j = 0; j < 4; ++j) {
            int bb = mi * 16 + (lane >> 4) * 4 + j;
            int n = lane & 15;
            float v = cfs[bb][0] * acc[0][mi][j] + cfs[bb][1] * acc[1][mi][j] +
                      cfs[bb][2] * acc[2][mi][j] + cfs[bb][3] * acc[3][mi][j];
            v += (float)xi[((size_t)t * B_ + bb) * G4 + g * H_ + jb * 16 + n];
            gl[g][bb][n] = v;
        }
    __syncthreads();
    // cell update for (64 b x 16 cols); h[t] written into xi[t] gate-0 region
    for (int p = tid; p < 64 * 16; p += 256) {
        int bb = p >> 4, n = p & 15;
        int col = jb * 16 + n;
        float ig = gl[0][bb][n], fg = gl[1][bb][n], gg = gl[2][bb][n], og = gl[3][bb][n];
        float c = sigmoidf_(fg) * cstate[bb * H_ + col] + sigmoidf_(ig) * tanhf(gg);
        float h = sigmoidf_(og) * tanhf(c);
        cstate[bb * H_ + col] = c;
        hstate[bb * H_ + col] = h;
        xi[((size_t)t * B_ + bb) * G4 + col] = (f16)h;
    }
}

// ---------------- output projection ------------------------------------------
// Block (nt, t): rows = all 64 b at this t, cols = 64 of 128 C; 4 experts mixed
// in epilogue with per-row coef. hs[t] lives in xi[t]'s gate-0 region (stride G4).
__global__ __launch_bounds__(256, 1) void k_out_gemm(
        const f16* __restrict__ hs, const f16* __restrict__ Woh,
        const float* __restrict__ coef, const float* __restrict__ bom,
        float* __restrict__ out) {
    __shared__ f16 As[64 * 72];
    __shared__ f16 Bs[256 * 72];
    __shared__ float cfs[64][4];
    const int nt = blockIdx.x;   // 0..1
    const int t  = blockIdx.y;   // 0..255
    const int tid = threadIdx.x, lane = tid & 63, w = tid >> 6;
    cfs[tid >> 2][tid & 3] = coef[tid];

    f32x4 acc[4][4];
#pragma unroll
    for (int e = 0; e < 4; ++e)
#pragma unroll
        for (int mi = 0; mi < 4; ++mi) acc[e][mi] = 0.f;

    for (int kk = 0; kk < H_; kk += 64) {
        __syncthreads();
#pragma unroll
        for (int it = 0; it < 2; ++it) {   // A: hs[t] 64x64 (stride G4 overlay)
            int chunk = it * 256 + tid;
            int row = chunk >> 3, c8 = chunk & 7;
            *reinterpret_cast<f16x8*>(&As[row * 72 + c8 * 8]) =
                *reinterpret_cast<const f16x8*>(&hs[((size_t)t * B_ + row) * G4 + kk + c8 * 8]);
        }
#pragma unroll
        for (int it = 0; it < 8; ++it) {   // B: Wo rows e*C + nt*64 + n, 256x64
            int chunk = it * 256 + tid;
            int r = chunk >> 3, c8 = chunk & 7;
            int e = r >> 6, n = r & 63;
            size_t grow = (size_t)e * C_ + nt * 64 + n;
            *reinterpret_cast<f16x8*>(&Bs[r * 72 + c8 * 8]) =
                *reinterpret_cast<const f16x8*>(&Woh[grow * H_ + kk + c8 * 8]);
        }
        __syncthreads();
#pragma unroll
        for (int ks = 0; ks < 2; ++ks) {
            int ko = ks * 32 + (lane >> 4) * 8;
            f16x8 a[4];
#pragma unroll
            for (int mi = 0; mi < 4; ++mi)
                a[mi] = *reinterpret_cast<const f16x8*>(&As[(mi * 16 + (lane & 15)) * 72 + ko]);
#pragma unroll
            for (int e = 0; e < 4; ++e) {
                f16x8 bf = *reinterpret_cast<const f16x8*>(&Bs[(e * 64 + w * 16 + (lane & 15)) * 72 + ko]);
#pragma unroll
                for (int mi = 0; mi < 4; ++mi)
                    acc[e][mi] = __builtin_amdgcn_mfma_f32_16x16x32_f16(a[mi], bf, acc[e][mi], 0, 0, 0);
            }
        }
    }
#pragma unroll
    for (int mi = 0; mi < 4; ++mi)
#pragma unroll
        for (int j = 0; j < 4; ++j) {
            int bb = mi * 16 + (lane >> 4) * 4 + j;
            int cc = nt * 64 + w * 16 + (lane & 15);
            float v = cfs[bb][0] * acc[0][mi][j] + cfs[bb][1] * acc[1][mi][j] +
                      cfs[bb][2] * acc[2][mi][j] + cfs[bb][3] * acc[3][mi][j];
            v += bom[bb * C_ + cc];
            out[((size_t)t * B_ + bb) * C_ + cc] = v;
        }
}

// ---------------- finalize hT / cT -------------------------------------------
__global__ void k_finalize(const float* __restrict__ hstate, const float* __restrict__ cstate,
                           float* __restrict__ out) {
    int i = blockIdx.x * blockDim.x + threadIdx.x;
    if (i < B_ * H_) {
        out[(size_t)T_ * B_ * C_ + i] = hstate[i];
        out[(size_t)T_ * B_ * C_ + B_ * H_ + i] = cstate[i];
    }
}

extern "C" void kernel_launch(void* const* d_in, const int* in_sizes, int n_in,
                              void* d_out, int out_size, void* d_ws, size_t ws_size,
                              hipStream_t stream) {
    const float* x    = (const float*)d_in[0];
    const float* h0   = (const float*)d_in[1];
    const float* c0   = (const float*)d_in[2];
    const float* coef = (const float*)d_in[3];
    const float* Wi   = (const float*)d_in[4];
    const float* bi   = (const float*)d_in[5];
    const float* Wh   = (const float*)d_in[6];
    const float* bh   = (const float*)d_in[7];
    const float* Wo   = (const float*)d_in[8];
    const float* bo   = (const float*)d_in[9];
    float* out = (float*)d_out;

    // Workspace carve. Mandatory set ~170.7 MB; optional f16 staging copies of
    // Wi (+33.5 MB) and x (+33.5 MB) are carved only if ws_size has room.
    char* base = (char*)d_ws;
    size_t off = 0;
    auto carve = [&](size_t bytes) -> char* {
        char* r = base + off;
        off = (off + bytes + 255) & ~(size_t)255;
        return r;
    };
    const size_t SZ_XI  = (size_t)T_ * B_ * G4 * 2;   // 134.2 MB (gate-0 doubles as hs)
    const size_t SZ_WHH = (size_t)E_ * G4 * H_ * 2;   // 33.5 MB
    const size_t SZ_WOH = (size_t)E_ * C_ * H_ * 2;   // 1 MB
    const size_t SZ_WIH = (size_t)E_ * G4 * I_ * 2;   // 33.5 MB (optional)
    const size_t SZ_XH  = (size_t)T_ * B_ * I_ * 2;   // 33.5 MB (optional)

    f16*   xi     = (f16*)carve(SZ_XI);
    f16*   Whh    = (f16*)carve(SZ_WHH);
    f16*   Woh    = (f16*)carve(SZ_WOH);
    f16*   h0h    = (f16*)carve((size_t)B_ * H_ * 2);
    float* gbias  = (float*)carve((size_t)B_ * G4 * 4);
    float* bom    = (float*)carve((size_t)B_ * C_ * 4);
    float* hstate = (float*)carve((size_t)B_ * H_ * 4);
    float* cstate = (float*)carve((size_t)B_ * H_ * 4);

    f16* Wih = nullptr;
    f16* xh  = nullptr;
    if (off + SZ_WIH + 256 <= ws_size) Wih = (f16*)carve(SZ_WIH);
    if (Wih && off + SZ_XH + 256 <= ws_size) xh = (f16*)carve(SZ_XH);
    (void)in_sizes; (void)n_in; (void)out_size;

    // conversions
    if (xh)  k_f32_to_f16<<<2048, 256, 0, stream>>>(x,  xh,  (T_ * B_ * I_) / 8);
    if (Wih) k_f32_to_f16<<<2048, 256, 0, stream>>>(Wi, Wih, (E_ * G4 * I_) / 8);
    k_f32_to_f16<<<2048, 256, 0, stream>>>(Wh, Whh, (E_ * G4 * H_) / 8);
    k_f32_to_f16<<<512,  256, 0, stream>>>(Wo, Woh, (E_ * C_ * H_) / 8);
    k_mix_biases<<<512, 256, 0, stream>>>(coef, bi, bh, bo, gbias, bom);
    k_init_state<<<(B_ * H_ + 255) / 256, 256, 0, stream>>>(h0, c0, hstate, cstate, h0h);

    // xi = mixed input projection (+ all biases folded in)
    dim3 gx(32, 64);
    if (xh)
        k_xi_gemm<true,  true ><<<gx, 256, 0, stream>>>(xh, nullptr, Wih, nullptr, coef, gbias, xi);
    else if (Wih)
        k_xi_gemm<false, true ><<<gx, 256, 0, stream>>>(nullptr, x, Wih, nullptr, coef, gbias, xi);
    else
        k_xi_gemm<false, false><<<gx, 256, 0, stream>>>(nullptr, x, nullptr, Wi, coef, gbias, xi);

    // serial recurrence (h[t] overlaid into xi[t] gate-0)
    for (int t = 0; t < T_; ++t)
        k_rec_step<<<64, 256, 0, stream>>>(t, Whh, h0h, xi, coef, hstate, cstate);

    // output projection
    dim3 go(2, 256);
    k_out_gemm<<<go, 256, 0, stream>>>(xi, Woh, coef, bom, out);

    k_finalize<<<(B_ * H_ + 255) / 256, 256, 0, stream>>>(hstate, cstate, out);
}

// Round 3
// 4123.608 us; speedup vs baseline: 1.5394x; 1.5394x over previous
//
#include <hip/hip_runtime.h>
#include <hip/hip_fp16.h>
#include <cstdint>

// Problem constants
#define T_  256
#define B_  64
#define I_  1024
#define H_  1024
#define E_  4
#define C_  128
#define G4  4096   // 4*H

typedef _Float16 f16;
typedef _Float16 f16x8 __attribute__((ext_vector_type(8)));
typedef float    f32x4 __attribute__((ext_vector_type(4)));

__device__ __forceinline__ float sigmoidf_(float x) { return 1.f / (1.f + __expf(-x)); }

// ---------------- conversion f32 -> f16 (vectorized, grid-stride) -------------
__global__ void k_f32_to_f16(const float* __restrict__ src, f16* __restrict__ dst, int n8) {
    int i = blockIdx.x * blockDim.x + threadIdx.x;
    int stride = gridDim.x * blockDim.x;
    for (; i < n8; i += stride) {
        const float4* s = reinterpret_cast<const float4*>(src) + (size_t)i * 2;
        float4 a = s[0], b = s[1];
        f16x8 v = { (f16)a.x, (f16)a.y, (f16)a.z, (f16)a.w,
                    (f16)b.x, (f16)b.y, (f16)b.z, (f16)b.w };
        *reinterpret_cast<f16x8*>(dst + (size_t)i * 8) = v;
    }
}

// ---------------- mixed biases: gbias = coef@(bi+bh), bom = coef@bo ----------
__global__ void k_mix_biases(const float* __restrict__ coef, const float* __restrict__ bi,
                             const float* __restrict__ bh, const float* __restrict__ bo,
                             float* __restrict__ gbias, float* __restrict__ bom) {
    int idx = blockIdx.x * blockDim.x + threadIdx.x;
    int stride = gridDim.x * blockDim.x;
    for (int i = idx; i < B_ * G4; i += stride) {
        int b = i >> 12, o = i & (G4 - 1);
        float s = 0.f;
#pragma unroll
        for (int e = 0; e < 4; ++e) s += coef[b * 4 + e] * (bi[e * G4 + o] + bh[e * G4 + o]);
        gbias[i] = s;
    }
    for (int i = idx; i < B_ * C_; i += stride) {
        int b = i >> 7, c = i & (C_ - 1);
        float s = 0.f;
#pragma unroll
        for (int e = 0; e < 4; ++e) s += coef[b * 4 + e] * bo[e * C_ + c];
        bom[i] = s;
    }
}

// ---------------- state init -------------------------------------------------
__global__ void k_init_state(const float* __restrict__ h0, const float* __restrict__ c0,
                             float* __restrict__ hstate, float* __restrict__ cstate,
                             f16* __restrict__ h0h) {
    int i = blockIdx.x * blockDim.x + threadIdx.x;
    if (i < B_ * H_) {
        float h = h0[i];
        hstate[i] = h; cstate[i] = c0[i]; h0h[i] = (f16)h;
    }
}

// ---------------- xi GEMM: per-sample mixed input projection -----------------
// Per block: b fixed, all T=256 rows, 128 output cols; weights mixed during
// staging, so FLOPs = 137G not 549G. Templated on whether x / Wi have been
// pre-converted to f16 (workspace-size dependent).
template<bool XF16, bool WF16>
__global__ __launch_bounds__(256, 1) void k_xi_gemm(
        const f16* __restrict__ xh, const float* __restrict__ xf,
        const f16* __restrict__ Wih, const float* __restrict__ Wif,
        const float* __restrict__ coef, const float* __restrict__ gbias,
        f16* __restrict__ xi) {
    __shared__ f16 As[256 * 72];
    __shared__ f16 Bs[128 * 72];
    const int nt = blockIdx.x;      // 0..31  (128-col tile of 4096)
    const int b  = blockIdx.y;      // 0..63
    const int tid = threadIdx.x;
    const int lane = tid & 63, wave = tid >> 6;
    const int wr = wave >> 1, wc = wave & 1;

    float cf[4];
#pragma unroll
    for (int e = 0; e < 4; ++e) cf[e] = coef[b * 4 + e];

    f32x4 acc[8][4];
#pragma unroll
    for (int mi = 0; mi < 8; ++mi)
#pragma unroll
        for (int ni = 0; ni < 4; ++ni) acc[mi][ni] = 0.f;

    for (int kk = 0; kk < I_; kk += 64) {
        __syncthreads();
        // stage A: x[t, b, kk..kk+64)  (256 rows x 64)
#pragma unroll
        for (int it = 0; it < 8; ++it) {
            int chunk = it * 256 + tid;
            int row = chunk >> 3, c8 = chunk & 7;
            if constexpr (XF16) {
                *reinterpret_cast<f16x8*>(&As[row * 72 + c8 * 8]) =
                    *reinterpret_cast<const f16x8*>(&xh[((size_t)row * B_ + b) * I_ + kk + c8 * 8]);
            } else {
                const float4* p = reinterpret_cast<const float4*>(&xf[((size_t)row * B_ + b) * I_ + kk + c8 * 8]);
                float4 a = p[0], bq = p[1];
                f16x8 v = { (f16)a.x, (f16)a.y, (f16)a.z, (f16)a.w,
                            (f16)bq.x, (f16)bq.y, (f16)bq.z, (f16)bq.w };
                *reinterpret_cast<f16x8*>(&As[row * 72 + c8 * 8]) = v;
            }
        }
        // stage B mixed: sum_e coef[b,e]*Wi[e, col, kk..]  (128 rows x 64)
#pragma unroll
        for (int it = 0; it < 4; ++it) {
            int chunk = it * 256 + tid;
            int n = chunk >> 3, c8 = chunk & 7;
            if constexpr (WF16) {
                size_t base = ((size_t)(nt * 128 + n)) * I_ + kk + c8 * 8;
                f16 c0 = (f16)cf[0], c1 = (f16)cf[1], c2 = (f16)cf[2], c3 = (f16)cf[3];
                f16x8 w0 = *reinterpret_cast<const f16x8*>(&Wih[base]);
                f16x8 w1 = *reinterpret_cast<const f16x8*>(&Wih[base + (size_t)1 * G4 * I_]);
                f16x8 w2 = *reinterpret_cast<const f16x8*>(&Wih[base + (size_t)2 * G4 * I_]);
                f16x8 w3 = *reinterpret_cast<const f16x8*>(&Wih[base + (size_t)3 * G4 * I_]);
                f16x8 m = w0 * c0 + w1 * c1 + w2 * c2 + w3 * c3;
                *reinterpret_cast<f16x8*>(&Bs[n * 72 + c8 * 8]) = m;
            } else {
                size_t base = ((size_t)(nt * 128 + n)) * I_ + kk + c8 * 8;
                float m[8];
#pragma unroll
                for (int j = 0; j < 8; ++j) m[j] = 0.f;
#pragma unroll
                for (int e = 0; e < 4; ++e) {
                    const float4* p = reinterpret_cast<const float4*>(&Wif[base + (size_t)e * G4 * I_]);
                    float4 a = p[0], bq = p[1];
                    m[0] += cf[e] * a.x;  m[1] += cf[e] * a.y;
                    m[2] += cf[e] * a.z;  m[3] += cf[e] * a.w;
                    m[4] += cf[e] * bq.x; m[5] += cf[e] * bq.y;
                    m[6] += cf[e] * bq.z; m[7] += cf[e] * bq.w;
                }
                f16x8 v = { (f16)m[0], (f16)m[1], (f16)m[2], (f16)m[3],
                            (f16)m[4], (f16)m[5], (f16)m[6], (f16)m[7] };
                *reinterpret_cast<f16x8*>(&Bs[n * 72 + c8 * 8]) = v;
            }
        }
        __syncthreads();
#pragma unroll
        for (int ks = 0; ks < 2; ++ks) {
            int ko = ks * 32 + (lane >> 4) * 8;
            f16x8 a[8], bb[4];
#pragma unroll
            for (int mi = 0; mi < 8; ++mi)
                a[mi] = *reinterpret_cast<const f16x8*>(&As[(wr * 128 + mi * 16 + (lane & 15)) * 72 + ko]);
#pragma unroll
            for (int ni = 0; ni < 4; ++ni)
                bb[ni] = *reinterpret_cast<const f16x8*>(&Bs[(wc * 64 + ni * 16 + (lane & 15)) * 72 + ko]);
#pragma unroll
            for (int mi = 0; mi < 8; ++mi)
#pragma unroll
                for (int ni = 0; ni < 4; ++ni)
                    acc[mi][ni] = __builtin_amdgcn_mfma_f32_16x16x32_f16(a[mi], bb[ni], acc[mi][ni], 0, 0, 0);
        }
    }
    // epilogue: add mixed bias (coef@(bi+bh) folded in), store f16
#pragma unroll
    for (int mi = 0; mi < 8; ++mi)
#pragma unroll
        for (int ni = 0; ni < 4; ++ni)
#pragma unroll
            for (int j = 0; j < 4; ++j) {
                int t = wr * 128 + mi * 16 + (lane >> 4) * 4 + j;
                int o = nt * 128 + wc * 64 + ni * 16 + (lane & 15);
                float v = acc[mi][ni][j] + gbias[b * G4 + o];
                xi[((size_t)t * B_ + b) * G4 + o] = (f16)v;
            }
}

// ---------------- recurrence step (256 blocks = 1 per CU) ---------------------
// Block jb owns 4 h-columns. It computes ALL 16 gate-expert rows for those
// columns: rows r = e*16 + g*4 + c of a 64-row x K=1024 GEMM vs h_prev[64,1024].
// Wave w = expert w (N-tile of 16 = {g,c} pairs). Expert mix is a cross-wave
// LDS combine; the cell update is block-local. h[t] overlays xi[t] gate-0
// (block jb touches only cols jb*4..+4; other blocks disjoint -> race-free;
// kernel boundary gives cross-step visibility).
// Per block per step: 131KB Whh slice (distinct per block -> ~4.2MB/XCD,
// L2-resident across steps) + 128KB h_prev (shared, L2-hit).
__global__ __launch_bounds__(256, 1) void k_rec_step(
        int t, const f16* __restrict__ Whh, const f16* __restrict__ h0h,
        f16* xi, const float* __restrict__ coef,
        float* __restrict__ hstate, float* __restrict__ cstate) {
    __shared__ f16 As[64 * 72];
    __shared__ f16 Bs[64 * 72];
    __shared__ float gl[4][64][17];   // [expert][b][g*4+c], padded
    __shared__ float cfs[64][4];
    const int jb = blockIdx.x;               // 0..255, h-cols jb*4..jb*4+3
    const int tid = threadIdx.x, lane = tid & 63, w = tid >> 6;  // wave = expert
    cfs[tid >> 2][tid & 3] = coef[tid];

    const f16* hprev;
    size_t hstr;
    if (t == 0) { hprev = h0h;                            hstr = H_; }
    else        { hprev = xi + (size_t)(t - 1) * B_ * G4; hstr = G4; }

    f32x4 acc[4];
#pragma unroll
    for (int mi = 0; mi < 4; ++mi) acc[mi] = 0.f;

    for (int kk = 0; kk < H_; kk += 64) {
        __syncthreads();
#pragma unroll
        for (int it = 0; it < 2; ++it) {   // A: h_prev 64x64
            int chunk = it * 256 + tid;
            int row = chunk >> 3, c8 = chunk & 7;
            *reinterpret_cast<f16x8*>(&As[row * 72 + c8 * 8]) =
                *reinterpret_cast<const f16x8*>(&hprev[(size_t)row * hstr + kk + c8 * 8]);
        }
#pragma unroll
        for (int it = 0; it < 2; ++it) {   // B: 64 rows (e,g,c) x 64
            int chunk = it * 256 + tid;
            int r = chunk >> 3, c8 = chunk & 7;
            int e = r >> 4, g = (r >> 2) & 3, c = r & 3;
            size_t grow = (size_t)e * G4 + g * H_ + jb * 4 + c;
            *reinterpret_cast<f16x8*>(&Bs[r * 72 + c8 * 8]) =
                *reinterpret_cast<const f16x8*>(&Whh[grow * H_ + kk + c8 * 8]);
        }
        __syncthreads();
#pragma unroll
        for (int ks = 0; ks < 2; ++ks) {
            int ko = ks * 32 + (lane >> 4) * 8;
            f16x8 bf = *reinterpret_cast<const f16x8*>(&Bs[(w * 16 + (lane & 15)) * 72 + ko]);
#pragma unroll
            for (int mi = 0; mi < 4; ++mi) {
                f16x8 a = *reinterpret_cast<const f16x8*>(&As[(mi * 16 + (lane & 15)) * 72 + ko]);
                acc[mi] = __builtin_amdgcn_mfma_f32_16x16x32_f16(a, bf, acc[mi], 0, 0, 0);
            }
        }
    }
    // park per-expert gate values in LDS
#pragma unroll
    for (int mi = 0; mi < 4; ++mi)
#pragma unroll
        for (int j = 0; j < 4; ++j) {
            int bb = mi * 16 + (lane >> 4) * 4 + j;
            gl[w][bb][lane & 15] = acc[mi][j];
        }
    __syncthreads();
    // mix experts + add xi + cell update: thread p -> (b = p>>2, c = p&3)
    {
        int bb = tid >> 2, cl = tid & 3;
        int col = jb * 4 + cl;
        float gate[4];
#pragma unroll
        for (int g = 0; g < 4; ++g) {
            int n = g * 4 + cl;
            float v = cfs[bb][0] * gl[0][bb][n] + cfs[bb][1] * gl[1][bb][n] +
                      cfs[bb][2] * gl[2][bb][n] + cfs[bb][3] * gl[3][bb][n];
            v += (float)xi[((size_t)t * B_ + bb) * G4 + g * H_ + col];
            gate[g] = v;
        }
        float c = sigmoidf_(gate[1]) * cstate[bb * H_ + col] + sigmoidf_(gate[0]) * tanhf(gate[2]);
        float h = sigmoidf_(gate[3]) * tanhf(c);
        cstate[bb * H_ + col] = c;
        hstate[bb * H_ + col] = h;
        xi[((size_t)t * B_ + bb) * G4 + col] = (f16)h;   // h[t] overlay (gate-0)
    }
}

// ---------------- output projection ------------------------------------------
// Block (nt, t): rows = all 64 b at this t, cols = 64 of 128 C; 4 experts mixed
// in epilogue with per-row coef. hs[t] lives in xi[t]'s gate-0 region (stride G4).
__global__ __launch_bounds__(256, 1) void k_out_gemm(
        const f16* __restrict__ hs, const f16* __restrict__ Woh,
        const float* __restrict__ coef, const float* __restrict__ bom,
        float* __restrict__ out) {
    __shared__ f16 As[64 * 72];
    __shared__ f16 Bs[256 * 72];
    __shared__ float cfs[64][4];
    const int nt = blockIdx.x;   // 0..1
    const int t  = blockIdx.y;   // 0..255
    const int tid = threadIdx.x, lane = tid & 63, w = tid >> 6;
    cfs[tid >> 2][tid & 3] = coef[tid];

    f32x4 acc[4][4];
#pragma unroll
    for (int e = 0; e < 4; ++e)
#pragma unroll
        for (int mi = 0; mi < 4; ++mi) acc[e][mi] = 0.f;

    for (int kk = 0; kk < H_; kk += 64) {
        __syncthreads();
#pragma unroll
        for (int it = 0; it < 2; ++it) {   // A: hs[t] 64x64 (stride G4 overlay)
            int chunk = it * 256 + tid;
            int row = chunk >> 3, c8 = chunk & 7;
            *reinterpret_cast<f16x8*>(&As[row * 72 + c8 * 8]) =
                *reinterpret_cast<const f16x8*>(&hs[((size_t)t * B_ + row) * G4 + kk + c8 * 8]);
        }
#pragma unroll
        for (int it = 0; it < 8; ++it) {   // B: Wo rows e*C + nt*64 + n, 256x64
            int chunk = it * 256 + tid;
            int r = chunk >> 3, c8 = chunk & 7;
            int e = r >> 6, n = r & 63;
            size_t grow = (size_t)e * C_ + nt * 64 + n;
            *reinterpret_cast<f16x8*>(&Bs[r * 72 + c8 * 8]) =
                *reinterpret_cast<const f16x8*>(&Woh[grow * H_ + kk + c8 * 8]);
        }
        __syncthreads();
#pragma unroll
        for (int ks = 0; ks < 2; ++ks) {
            int ko = ks * 32 + (lane >> 4) * 8;
            f16x8 a[4];
#pragma unroll
            for (int mi = 0; mi < 4; ++mi)
                a[mi] = *reinterpret_cast<const f16x8*>(&As[(mi * 16 + (lane & 15)) * 72 + ko]);
#pragma unroll
            for (int e = 0; e < 4; ++e) {
                f16x8 bf = *reinterpret_cast<const f16x8*>(&Bs[(e * 64 + w * 16 + (lane & 15)) * 72 + ko]);
#pragma unroll
                for (int mi = 0; mi < 4; ++mi)
                    acc[e][mi] = __builtin_amdgcn_mfma_f32_16x16x32_f16(a[mi], bf, acc[e][mi], 0, 0, 0);
            }
        }
    }
#pragma unroll
    for (int mi = 0; mi < 4; ++mi)
#pragma unroll
        for (int j = 0; j < 4; ++j) {
            int bb = mi * 16 + (lane >> 4) * 4 + j;
            int cc = nt * 64 + w * 16 + (lane & 15);
            float v = cfs[bb][0] * acc[0][mi][j] + cfs[bb][1] * acc[1][mi][j] +
                      cfs[bb][2] * acc[2][mi][j] + cfs[bb][3] * acc[3][mi][j];
            v += bom[bb * C_ + cc];
            out[((size_t)t * B_ + bb) * C_ + cc] = v;
        }
}

// ---------------- finalize hT / cT -------------------------------------------
__global__ void k_finalize(const float* __restrict__ hstate, const float* __restrict__ cstate,
                           float* __restrict__ out) {
    int i = blockIdx.x * blockDim.x + threadIdx.x;
    if (i < B_ * H_) {
        out[(size_t)T_ * B_ * C_ + i] = hstate[i];
        out[(size_t)T_ * B_ * C_ + B_ * H_ + i] = cstate[i];
    }
}

extern "C" void kernel_launch(void* const* d_in, const int* in_sizes, int n_in,
                              void* d_out, int out_size, void* d_ws, size_t ws_size,
                              hipStream_t stream) {
    const float* x    = (const float*)d_in[0];
    const float* h0   = (const float*)d_in[1];
    const float* c0   = (const float*)d_in[2];
    const float* coef = (const float*)d_in[3];
    const float* Wi   = (const float*)d_in[4];
    const float* bi   = (const float*)d_in[5];
    const float* Wh   = (const float*)d_in[6];
    const float* bh   = (const float*)d_in[7];
    const float* Wo   = (const float*)d_in[8];
    const float* bo   = (const float*)d_in[9];
    float* out = (float*)d_out;

    // Workspace carve. Mandatory set ~170.7 MB; optional f16 staging copies of
    // Wi (+33.5 MB) and x (+33.5 MB) are carved only if ws_size has room.
    char* base = (char*)d_ws;
    size_t off = 0;
    auto carve = [&](size_t bytes) -> char* {
        char* r = base + off;
        off = (off + bytes + 255) & ~(size_t)255;
        return r;
    };
    const size_t SZ_XI  = (size_t)T_ * B_ * G4 * 2;   // 134.2 MB (gate-0 doubles as hs)
    const size_t SZ_WHH = (size_t)E_ * G4 * H_ * 2;   // 33.5 MB
    const size_t SZ_WOH = (size_t)E_ * C_ * H_ * 2;   // 1 MB
    const size_t SZ_WIH = (size_t)E_ * G4 * I_ * 2;   // 33.5 MB (optional)
    const size_t SZ_XH  = (size_t)T_ * B_ * I_ * 2;   // 33.5 MB (optional)

    f16*   xi     = (f16*)carve(SZ_XI);
    f16*   Whh    = (f16*)carve(SZ_WHH);
    f16*   Woh    = (f16*)carve(SZ_WOH);
    f16*   h0h    = (f16*)carve((size_t)B_ * H_ * 2);
    float* gbias  = (float*)carve((size_t)B_ * G4 * 4);
    float* bom    = (float*)carve((size_t)B_ * C_ * 4);
    float* hstate = (float*)carve((size_t)B_ * H_ * 4);
    float* cstate = (float*)carve((size_t)B_ * H_ * 4);

    f16* Wih = nullptr;
    f16* xh  = nullptr;
    if (off + SZ_WIH + 256 <= ws_size) Wih = (f16*)carve(SZ_WIH);
    if (Wih && off + SZ_XH + 256 <= ws_size) xh = (f16*)carve(SZ_XH);
    (void)in_sizes; (void)n_in; (void)out_size;

    // conversions
    if (xh)  k_f32_to_f16<<<2048, 256, 0, stream>>>(x,  xh,  (T_ * B_ * I_) / 8);
    if (Wih) k_f32_to_f16<<<2048, 256, 0, stream>>>(Wi, Wih, (E_ * G4 * I_) / 8);
    k_f32_to_f16<<<2048, 256, 0, stream>>>(Wh, Whh, (E_ * G4 * H_) / 8);
    k_f32_to_f16<<<512,  256, 0, stream>>>(Wo, Woh, (E_ * C_ * H_) / 8);
    k_mix_biases<<<512, 256, 0, stream>>>(coef, bi, bh, bo, gbias, bom);
    k_init_state<<<(B_ * H_ + 255) / 256, 256, 0, stream>>>(h0, c0, hstate, cstate, h0h);

    // xi = mixed input projection (+ all biases folded in)
    dim3 gx(32, 64);
    if (xh)
        k_xi_gemm<true,  true ><<<gx, 256, 0, stream>>>(xh, nullptr, Wih, nullptr, coef, gbias, xi);
    else if (Wih)
        k_xi_gemm<false, true ><<<gx, 256, 0, stream>>>(nullptr, x, Wih, nullptr, coef, gbias, xi);
    else
        k_xi_gemm<false, false><<<gx, 256, 0, stream>>>(nullptr, x, nullptr, Wi, coef, gbias, xi);

    // serial recurrence (h[t] overlaid into xi[t] gate-0), 256 blocks = 1/CU
    for (int t = 0; t < T_; ++t)
        k_rec_step<<<256, 256, 0, stream>>>(t, Whh, h0h, xi, coef, hstate, cstate);

    // output projection
    dim3 go(2, 256);
    k_out_gemm<<<go, 256, 0, stream>>>(xi, Woh, coef, bom, out);

    k_finalize<<<(B_ * H_ + 255) / 256, 256, 0, stream>>>(hstate, cstate, out);
}